// Round 4
// baseline (291.260 us; speedup 1.0000x reference)
//
#include <hip/hip_runtime.h>
#include <hip/hip_bf16.h>

// GCN backbone, bf16 datapath:
//   layer: g' = dinv .* (h@W) (MFMA bf16, f32 acc, dinv-prescaled bf16 out)
//          h  = relu(dn*(g'[node] + sum_col g'[col]) + b)
// Prescale folds the symmetric-norm coef into the GEMM epilogue, removing
// all per-edge dinv gathers (25% of agg sector traffic) and the coef FMULs.
// Agg is feature-sliced 4x32 (64B = 1 sector/slice) with XCD pinning via
// blockIdx%8 so each XCD's gather working set (3.2 MB) fits its 4 MiB L2
// (latency-wall fix: agg is bound by per-CU outstanding-sectors x latency).
// cols/hout use nontemporal ld/st to keep the slice resident in L2.
// CSR: u16 cols, no self-loops (analytic self term). Count uses 64B-padded
// counters (one per cache line) to kill TCC line serialization; count is
// fused with layer-1 GEMM, zero with prepW, dinv-rescale with fill.

#define TPB 256
#define CSTRIDE 16  // cnt padding: one counter per 64B line
typedef unsigned short u16;
typedef unsigned int u32;
typedef __attribute__((ext_vector_type(8))) __bf16 bf16x8;
typedef __attribute__((ext_vector_type(8))) u16 u16x8;
typedef __attribute__((ext_vector_type(4))) float f32x4;
typedef __attribute__((ext_vector_type(4))) u32 u32x4;  // clang vec (nontemporal-ok)

__device__ __forceinline__ u16 f2b(float f) {
    __bf16 b = (__bf16)f;                 // RNE on gfx950
    return __builtin_bit_cast(u16, b);
}
__device__ __forceinline__ float b2f_lo(u32 w) { return __builtin_bit_cast(float, w << 16); }
__device__ __forceinline__ float b2f_hi(u32 w) { return __builtin_bit_cast(float, w & 0xffff0000u); }

__device__ __forceinline__ bf16x8 cvt8(float4 u0, float4 u1) {
    u16x8 r;
    r[0] = f2b(u0.x); r[1] = f2b(u0.y); r[2] = f2b(u0.z); r[3] = f2b(u0.w);
    r[4] = f2b(u1.x); r[5] = f2b(u1.y); r[6] = f2b(u1.z); r[7] = f2b(u1.w);
    return __builtin_bit_cast(bf16x8, r);
}

// ---------------- CSR build pieces ----------------
__device__ __forceinline__ void countslot_body(int bid, const int* __restrict__ dst,
                                               int* cnt, u16* __restrict__ aux, int E) {
    int e = (bid * TPB + (int)threadIdx.x) * 4;
    if (e + 3 < E) {
        int4 d = *(const int4*)(dst + e);
        ushort4 a;
        a.x = (u16)atomicAdd(&cnt[d.x * CSTRIDE], 1);
        a.y = (u16)atomicAdd(&cnt[d.y * CSTRIDE], 1);
        a.z = (u16)atomicAdd(&cnt[d.z * CSTRIDE], 1);
        a.w = (u16)atomicAdd(&cnt[d.w * CSTRIDE], 1);
        *(ushort4*)(aux + e) = a;
    } else {
        for (; e < E; ++e) aux[e] = (u16)atomicAdd(&cnt[dst[e] * CSTRIDE], 1);
    }
}

__global__ __launch_bounds__(TPB) void k_scan1(const int* __restrict__ cnt, int* rowptr,
                                               int* bsum, int N) {
    __shared__ int tmp[TPB];
    int t = threadIdx.x;
    int i = blockIdx.x * TPB + t;
    int v = (i < N) ? cnt[(size_t)i * CSTRIDE] : 0;
    tmp[t] = v;
    __syncthreads();
    for (int off = 1; off < TPB; off <<= 1) {
        int y = (t >= off) ? tmp[t - off] : 0;
        __syncthreads();
        tmp[t] += y;
        __syncthreads();
    }
    if (i < N) rowptr[i] = tmp[t] - v;
    if (t == TPB - 1) bsum[blockIdx.x] = tmp[t];
}

__global__ __launch_bounds__(TPB) void k_scan2(int* bsum, int nb) {
    __shared__ int tmp[TPB];
    int t = threadIdx.x;
    int v = (t < nb) ? bsum[t] : 0;
    tmp[t] = v;
    __syncthreads();
    for (int off = 1; off < TPB; off <<= 1) {
        int y = (t >= off) ? tmp[t - off] : 0;
        __syncthreads();
        tmp[t] += y;
        __syncthreads();
    }
    if (t < nb) bsum[t] = tmp[t] - v;
}

__global__ __launch_bounds__(TPB) void k_scan3(int* rowptr, const int* __restrict__ bsum,
                                               const int* __restrict__ cnt, float* dinv,
                                               int N, int total) {
    int i = blockIdx.x * TPB + threadIdx.x;
    if (i < N) {
        rowptr[i] += bsum[blockIdx.x];
        dinv[i] = 1.0f / sqrtf((float)(cnt[(size_t)i * CSTRIDE] + 1));  // +1 self-loop
    }
    if (i == 0) rowptr[N] = total;
}

// fused: blocks [0,nbF) fill CSR cols; blocks [nbF, nbF+nbS) rescale the
// layer-1 GEMM output by dinv (g' = dinv .* g), hidden under fill's scatter.
__global__ __launch_bounds__(TPB) void k_fill_scale(const int* __restrict__ src,
                                                    const int* __restrict__ dst,
                                                    const int* __restrict__ rowptr,
                                                    const u16* __restrict__ aux,
                                                    u16* __restrict__ cols, int E, int nbF,
                                                    u16* __restrict__ g,
                                                    const float* __restrict__ dinv, int N) {
    int b = blockIdx.x;
    if (b < nbF) {
        int e = (b * TPB + (int)threadIdx.x) * 4;
        if (e + 3 < E) {
            int4 s = *(const int4*)(src + e);
            int4 d = *(const int4*)(dst + e);
            ushort4 a = *(const ushort4*)(aux + e);
            cols[rowptr[d.x] + a.x] = (u16)s.x;
            cols[rowptr[d.y] + a.y] = (u16)s.y;
            cols[rowptr[d.z] + a.z] = (u16)s.z;
            cols[rowptr[d.w] + a.w] = (u16)s.w;
        } else {
            for (; e < E; ++e) cols[rowptr[dst[e]] + aux[e]] = (u16)src[e];
        }
    } else {
        int e8 = (b - nbF) * TPB + (int)threadIdx.x;  // 8-element unit
        if (e8 < N * 16) {
            int row = e8 >> 4;
            int off = (e8 & 15) * 8;
            float dv = dinv[row];
            u16* p = g + (size_t)row * 128 + off;
            uint4 v = *(uint4*)p;
            uint4 o;
            o.x = (u32)f2b(dv * b2f_lo(v.x)) | ((u32)f2b(dv * b2f_hi(v.x)) << 16);
            o.y = (u32)f2b(dv * b2f_lo(v.y)) | ((u32)f2b(dv * b2f_hi(v.y)) << 16);
            o.z = (u32)f2b(dv * b2f_lo(v.z)) | ((u32)f2b(dv * b2f_hi(v.z)) << 16);
            o.w = (u32)f2b(dv * b2f_lo(v.w)) | ((u32)f2b(dv * b2f_hi(v.w)) << 16);
            *(uint4*)p = o;
        }
    }
}

// W[128][128] f32 (k-major) -> Wt bf16 transposed + chunk-XOR-swizzled.
__device__ __forceinline__ void prepw_body(int bb, const float* __restrict__ Wa,
                                           const float* __restrict__ Wb,
                                           const float* __restrict__ Wc,
                                           u16* __restrict__ Wta, u16* __restrict__ Wtb,
                                           u16* __restrict__ Wtc) {
    int m = bb >> 3;
    const float* W = m == 0 ? Wa : (m == 1 ? Wb : Wc);
    u16* Wt = m == 0 ? Wta : (m == 1 ? Wtb : Wtc);
    int t = (bb & 7) * TPB + (int)threadIdx.x;
    int n = t >> 4, c = t & 15;
    u16x8 r;
#pragma unroll
    for (int j = 0; j < 8; ++j) r[j] = f2b(W[(8 * c + j) * 128 + n]);
    int cs = c ^ (n & 15);
    *(u16x8*)(Wt + n * 128 + cs * 8) = r;
}

// fused: zero padded counters; prep 3 W matrices; zero row N of bufA/bufB
// (the gather target for masked/padding edges).
__global__ __launch_bounds__(TPB) void k_zero_prep(int* cnt, int N, int nbZ4,
                                                   const float* __restrict__ Wa,
                                                   const float* __restrict__ Wb,
                                                   const float* __restrict__ Wc,
                                                   u16* __restrict__ Wta,
                                                   u16* __restrict__ Wtb,
                                                   u16* __restrict__ Wtc,
                                                   u16* __restrict__ bufA,
                                                   u16* __restrict__ bufB) {
    int b = blockIdx.x;
    if (b < nbZ4) {
        int i = b * TPB + (int)threadIdx.x;
        if (i < N * (CSTRIDE / 4)) ((int4*)cnt)[i] = (int4){0, 0, 0, 0};
    } else if (b < nbZ4 + 24) {
        prepw_body(b - nbZ4, Wa, Wb, Wc, Wta, Wtb, Wtc);
    } else {
        int t = threadIdx.x;
        uint4 z = (uint4){0, 0, 0, 0};
        if (t < 16) *(uint4*)(bufA + (size_t)N * 128 + t * 8) = z;
        else if (t < 32) *(uint4*)(bufB + (size_t)N * 128 + (t - 16) * 8) = z;
    }
}

// ---------------- MFMA GEMM: C[N][128] = (A[N][128] @ W) [* dinv row] ------
template <bool F32IN, bool SCALE>
__device__ __forceinline__ void gemm_body(int bid, const void* __restrict__ Ain,
                                          const u16* __restrict__ Wt,
                                          u16* __restrict__ C, int N,
                                          const float* __restrict__ dinv) {
    __shared__ u16 Ws[128 * 128];  // 32 KB, pre-swizzled chunks
    int t = threadIdx.x;
    {
        const uint4* s = (const uint4*)Wt;
        uint4* d = (uint4*)Ws;
#pragma unroll
        for (int i = 0; i < 8; ++i) d[t + 256 * i] = s[t + 256 * i];
    }
    __syncthreads();
    int wave = t >> 6, lane = t & 63;
    int li = lane & 15, lq = lane >> 4;
    int r0 = bid * 128 + wave * 32;
    f32x4 acc[2][8];
#pragma unroll
    for (int i = 0; i < 2; ++i)
#pragma unroll
        for (int f = 0; f < 8; ++f) acc[i][f] = (f32x4){0.f, 0.f, 0.f, 0.f};

    int ra = r0 + li, rb = ra + 16;
    size_t ra_c = (size_t)(ra < N ? ra : N - 1);
    size_t rb_c = (size_t)(rb < N ? rb : N - 1);
#pragma unroll
    for (int kc = 0; kc < 4; ++kc) {
        int koff = 32 * kc + 8 * lq;
        bf16x8 a0, a1;
        if constexpr (F32IN) {
            const float* A = (const float*)Ain;
            const float4* p0 = (const float4*)(A + ra_c * 128 + koff);
            const float4* p1 = (const float4*)(A + rb_c * 128 + koff);
            a0 = cvt8(p0[0], p0[1]);
            a1 = cvt8(p1[0], p1[1]);
        } else {
            const u16* A = (const u16*)Ain;
            a0 = *(const bf16x8*)(A + ra_c * 128 + koff);
            a1 = *(const bf16x8*)(A + rb_c * 128 + koff);
        }
#pragma unroll
        for (int f = 0; f < 8; ++f) {
            int n = 16 * f + li;
            int chunk = (4 * kc + lq) ^ li;  // n&15 == li
            bf16x8 b = *(const bf16x8*)(Ws + n * 128 + chunk * 8);
            acc[0][f] = __builtin_amdgcn_mfma_f32_16x16x32_bf16(a0, b, acc[0][f], 0, 0, 0);
            acc[1][f] = __builtin_amdgcn_mfma_f32_16x16x32_bf16(a1, b, acc[1][f], 0, 0, 0);
        }
    }
#pragma unroll
    for (int ri = 0; ri < 2; ++ri)
#pragma unroll
        for (int r = 0; r < 4; ++r) {
            int row = r0 + 16 * ri + 4 * lq + r;
            if (row < N) {
                float dv = 1.0f;
                if constexpr (SCALE) dv = dinv[row];
#pragma unroll
                for (int f = 0; f < 8; ++f)
                    C[(size_t)row * 128 + 16 * f + li] = f2b(dv * acc[ri][f][r]);
            }
        }
}

template <bool F32IN, bool SCALE>
__global__ __launch_bounds__(TPB) void k_gemm(const void* __restrict__ Ain,
                                              const u16* __restrict__ Wt,
                                              u16* __restrict__ C, int N,
                                              const float* __restrict__ dinv) {
    gemm_body<F32IN, SCALE>(blockIdx.x, Ain, Wt, C, N, dinv);
}

// fused: blocks [0,nbG) run layer-1 GEMM (f32 input, unscaled: dinv not yet
// known); blocks [nbG,..) run the CSR count+slot pass.
__global__ __launch_bounds__(TPB) void k_gemm1_count(const void* __restrict__ x,
                                                     const u16* __restrict__ Wt1,
                                                     u16* __restrict__ C, int N, int nbG,
                                                     const int* __restrict__ dst,
                                                     int* cnt, u16* __restrict__ aux, int E) {
    int b = blockIdx.x;
    if (b < nbG) {
        gemm_body<true, false>(b, x, Wt1, C, N, nullptr);
    } else {
        countslot_body(b - nbG, dst, cnt, aux, E);
    }
}

// ------- aggregate (feature-sliced): h = relu(dn*(g'[node]+sum g'[col])+b) -
// 4 lanes/node, 64B feature slice per block. Slice s pinned to XCDs {s,s+4}
// via blockIdx%8 so each XCD's gather set (3.2MB) fits its 4MiB L2.
// cols via nontemporal loads, hout via nontemporal stores (no L2 pollution).
// Masked/padding edges gather zero-row N.
__global__ __launch_bounds__(TPB) void k_agg(const u16* __restrict__ g,
                                             const u16* __restrict__ cols,
                                             const int* __restrict__ rowptr,
                                             const float* __restrict__ dinv,
                                             const float* __restrict__ bias,
                                             u16* __restrict__ hout, int N) {
    int b = blockIdx.x;
    int x = b & 7, k = b >> 3;
    int chunk = 2 * k + (x >> 2);   // 64-node chunk
    int slice = x & 3;              // 32-feature (64B) slice
    int node = chunk * 64 + ((int)threadIdx.x >> 2);
    int lane = threadIdx.x & 3;     // 4 lanes x 16B = 64B slice
    if (node >= N) return;
    int fo = slice * 32 + lane * 8; // u16 offset within row
    int beg = rowptr[node], end = rowptr[node + 1];
    float dn = dinv[node];
    float a[8];
    {   // self term: g'[node] (dn applied once at the end)
        uint4 vs = *(const uint4*)(g + (size_t)node * 128 + fo);
        a[0] = b2f_lo(vs.x); a[1] = b2f_hi(vs.x);
        a[2] = b2f_lo(vs.y); a[3] = b2f_hi(vs.y);
        a[4] = b2f_lo(vs.z); a[5] = b2f_hi(vs.z);
        a[6] = b2f_lo(vs.w); a[7] = b2f_hi(vs.w);
    }
    for (int sb = beg; sb < end; sb += 64) {
        int m = end - sb;
        if (m > 64) m = 64;
        // ---- stage up to 64 cols (16 per lane), nontemporal ----
        int cg[16];
#pragma unroll
        for (int q = 0; q < 16; ++q) {
            int off = 4 * q + lane;
            if (4 * q < m) {  // group-uniform guard
                u16 c = __builtin_nontemporal_load(cols + sb + (off < m ? off : 0));
                cg[q] = (off < m) ? (int)c : N;
            } else {
                cg[q] = N;
            }
        }
        // ---- 4 chunks of 16 edges: issue 16 sc0 gathers, drain, add ----
#pragma unroll
        for (int t = 0; t < 4; ++t) {
            if (16 * t < m) {
                uint4 v[16];
#pragma unroll
                for (int u = 0; u < 16; ++u) {
                    int col = __shfl(cg[4 * t + (u >> 2)], u & 3, 4);
                    const u16* p = g + (size_t)col * 128 + fo;
                    asm volatile("global_load_dwordx4 %0, %1, off sc0"
                                 : "=v"(v[u]) : "v"(p));
                }
                asm volatile("s_waitcnt vmcnt(0)" ::: "memory");
                __builtin_amdgcn_sched_barrier(0);
#pragma unroll
                for (int u = 0; u < 16; ++u) {
                    a[0] += b2f_lo(v[u].x); a[1] += b2f_hi(v[u].x);
                    a[2] += b2f_lo(v[u].y); a[3] += b2f_hi(v[u].y);
                    a[4] += b2f_lo(v[u].z); a[5] += b2f_hi(v[u].z);
                    a[6] += b2f_lo(v[u].w); a[7] += b2f_hi(v[u].w);
                }
            }
        }
    }
    const float4* bp = (const float4*)(bias + fo);
    float4 b0 = bp[0], b1 = bp[1];
    a[0] = fmaxf(fmaf(dn, a[0], b0.x), 0.f); a[1] = fmaxf(fmaf(dn, a[1], b0.y), 0.f);
    a[2] = fmaxf(fmaf(dn, a[2], b0.z), 0.f); a[3] = fmaxf(fmaf(dn, a[3], b0.w), 0.f);
    a[4] = fmaxf(fmaf(dn, a[4], b1.x), 0.f); a[5] = fmaxf(fmaf(dn, a[5], b1.y), 0.f);
    a[6] = fmaxf(fmaf(dn, a[6], b1.z), 0.f); a[7] = fmaxf(fmaf(dn, a[7], b1.w), 0.f);
    u32x4 o;
    o.x = (u32)f2b(a[0]) | ((u32)f2b(a[1]) << 16);
    o.y = (u32)f2b(a[2]) | ((u32)f2b(a[3]) << 16);
    o.z = (u32)f2b(a[4]) | ((u32)f2b(a[5]) << 16);
    o.w = (u32)f2b(a[6]) | ((u32)f2b(a[7]) << 16);
    __builtin_nontemporal_store(o, (u32x4*)(hout + (size_t)node * 128 + fo));
}

// ---------------- pool (bounds fused: per-block binary search) ----------------
__global__ __launch_bounds__(128) void k_pool(const u16* __restrict__ h,
                                              const int* __restrict__ batch,
                                              float* __restrict__ out, int N, int G) {
    int g = blockIdx.x;
    int f = threadIdx.x;
    int beg, end;
    {
        int lo = 0, hi = N;
        while (lo < hi) { int m = (lo + hi) >> 1; if (batch[m] < g) lo = m + 1; else hi = m; }
        beg = lo;
        lo = 0; hi = N;
        int g1 = g + 1;
        while (lo < hi) { int m = (lo + hi) >> 1; if (batch[m] < g1) lo = m + 1; else hi = m; }
        end = lo;
    }
    float acc = 0.0f;
    for (int n = beg; n < end; ++n)
        acc += b2f_lo((u32)h[(size_t)n * 128 + f]);
    int c = end - beg; if (c < 1) c = 1;
    out[(size_t)g * 128 + f] = acc / (float)c;
}

extern "C" void kernel_launch(void* const* d_in, const int* in_sizes, int n_in,
                              void* d_out, int out_size, void* d_ws, size_t ws_size,
                              hipStream_t stream) {
    const float* x  = (const float*)d_in[0];
    const float* W1 = (const float*)d_in[2];
    const float* b1 = (const float*)d_in[3];
    const float* W2 = (const float*)d_in[4];
    const float* b2 = (const float*)d_in[5];
    const float* W3 = (const float*)d_in[6];
    const float* b3 = (const float*)d_in[7];
    const int* ei    = (const int*)d_in[8];
    const int* batch = (const int*)d_in[9];

    int N = in_sizes[0] / 128;
    int E = in_sizes[8] / 2;
    int G = out_size / 128;
    const int* src = ei;
    const int* dst = ei + E;

    char* w = (char*)d_ws;
    auto alloc = [&](size_t bytes) -> void* {
        void* p = (void*)w;
        w += (bytes + 255) & ~(size_t)255;
        return p;
    };
    int*   cnt    = (int*)alloc((size_t)N * CSTRIDE * 4);
    u16*   aux    = (u16*)alloc((size_t)E * 2);
    int*   rowptr = (int*)alloc((size_t)(N + 1) * 4);
    float* dinv   = (float*)alloc((size_t)N * 4);
    int*   bsum   = (int*)alloc(4096);
    u16*   cols   = (u16*)alloc((size_t)E * 2);
    u16*   Wt1    = (u16*)alloc(128 * 128 * 2);
    u16*   Wt2    = (u16*)alloc(128 * 128 * 2);
    u16*   Wt3    = (u16*)alloc(128 * 128 * 2);
    u16*   bufA   = (u16*)alloc((size_t)(N + 1) * 128 * 2);  // +1 zero row
    u16*   bufB   = (u16*)alloc((size_t)(N + 1) * 128 * 2);

    int nbN = (N + TPB - 1) / TPB;
    int nbE4 = (E / 4 + TPB - 1) / TPB;
    int nbG = (N + 127) / 128;
    int nbZ4 = (N * (CSTRIDE / 4) + TPB - 1) / TPB;
    int nbS = (N * 16 + TPB - 1) / TPB;
    int C64 = (N + 63) / 64;
    int nbAgg = 8 * ((C64 + 1) / 2);  // (chunk,slice) pairs, %8 -> XCD

    // ---- zero padded counters + weight prep + zero-row init (fused) ----
    k_zero_prep<<<nbZ4 + 24 + 1, TPB, 0, stream>>>(cnt, N, nbZ4, W1, W2, W3,
                                                   Wt1, Wt2, Wt3, bufA, bufB);
    // ---- layer-1 GEMM overlapped with CSR count+slot ----
    k_gemm1_count<<<nbG + nbE4, TPB, 0, stream>>>(x, Wt1, bufA, N, nbG, dst, cnt, aux, E);
    // ---- rowptr scan; fill fused with layer-1 dinv rescale ----
    k_scan1<<<nbN, TPB, 0, stream>>>(cnt, rowptr, bsum, N);
    k_scan2<<<1, TPB, 0, stream>>>(bsum, nbN);
    k_scan3<<<nbN, TPB, 0, stream>>>(rowptr, bsum, cnt, dinv, N, E);
    k_fill_scale<<<nbE4 + nbS, TPB, 0, stream>>>(src, dst, rowptr, aux, cols, E, nbE4,
                                                 bufA, dinv, N);

    // ---- 3 GCN layers ----
    k_agg<<<nbAgg, TPB, 0, stream>>>(bufA, cols, rowptr, dinv, b1, bufB, N);
    k_gemm<false, true><<<nbG, TPB, 0, stream>>>(bufB, Wt2, bufA, N, dinv);
    k_agg<<<nbAgg, TPB, 0, stream>>>(bufA, cols, rowptr, dinv, b2, bufB, N);
    k_gemm<false, true><<<nbG, TPB, 0, stream>>>(bufB, Wt3, bufA, N, dinv);
    k_agg<<<nbAgg, TPB, 0, stream>>>(bufA, cols, rowptr, dinv, b3, bufB, N);

    // ---- mean pool ----
    k_pool<<<G, 128, 0, stream>>>(bufB, batch, (float*)d_out, N, G);
}

// Round 5
// 212.718 us; speedup vs baseline: 1.3692x; 1.3692x over previous
//
#include <hip/hip_runtime.h>
#include <hip/hip_bf16.h>

// GCN backbone, bf16 datapath:
//   layer: g' = dinv .* (h@W) (MFMA bf16, f32 acc, dinv-prescaled bf16 out)
//          h  = relu(dn*(g'[node] + sum_col g'[col]) + b)
// Prescale folds the symmetric norm into the GEMM epilogue: agg has NO
// per-edge dinv gathers and NO coef multiplies (masked edges gather the
// zero row N). Agg = round-2 proven 16-lane/node structure + 2-deep
// software pipeline of 8-wide gather chunks with counted vmcnt(8) waits
// (static double buffers, no occupancy cap -> no spill-under-wait hazard).
// No nontemporal anywhere (round-4 lesson: pool reads agg output from L2).
// CSR: u16 cols, padded counters (1/64B line) for the atomic count pass,
// count fused with layer-1 GEMM, zero with prepW, dinv-rescale with fill.

#define TPB 256
#define CSTRIDE 16  // cnt padding: one counter per 64B line
typedef unsigned short u16;
typedef unsigned int u32;
typedef __attribute__((ext_vector_type(8))) __bf16 bf16x8;
typedef __attribute__((ext_vector_type(8))) u16 u16x8;
typedef __attribute__((ext_vector_type(4))) float f32x4;

__device__ __forceinline__ u16 f2b(float f) {
    __bf16 b = (__bf16)f;                 // RNE on gfx950
    return __builtin_bit_cast(u16, b);
}
__device__ __forceinline__ float b2f_lo(u32 w) { return __builtin_bit_cast(float, w << 16); }
__device__ __forceinline__ float b2f_hi(u32 w) { return __builtin_bit_cast(float, w & 0xffff0000u); }

__device__ __forceinline__ bf16x8 cvt8(float4 u0, float4 u1) {
    u16x8 r;
    r[0] = f2b(u0.x); r[1] = f2b(u0.y); r[2] = f2b(u0.z); r[3] = f2b(u0.w);
    r[4] = f2b(u1.x); r[5] = f2b(u1.y); r[6] = f2b(u1.z); r[7] = f2b(u1.w);
    return __builtin_bit_cast(bf16x8, r);
}

// ---------------- CSR build pieces ----------------
__device__ __forceinline__ void countslot_body(int bid, const int* __restrict__ dst,
                                               int* cnt, u16* __restrict__ aux, int E) {
    int e = (bid * TPB + (int)threadIdx.x) * 4;
    if (e + 3 < E) {
        int4 d = *(const int4*)(dst + e);
        ushort4 a;
        a.x = (u16)atomicAdd(&cnt[d.x * CSTRIDE], 1);
        a.y = (u16)atomicAdd(&cnt[d.y * CSTRIDE], 1);
        a.z = (u16)atomicAdd(&cnt[d.z * CSTRIDE], 1);
        a.w = (u16)atomicAdd(&cnt[d.w * CSTRIDE], 1);
        *(ushort4*)(aux + e) = a;
    } else {
        for (; e < E; ++e) aux[e] = (u16)atomicAdd(&cnt[dst[e] * CSTRIDE], 1);
    }
}

__global__ __launch_bounds__(TPB) void k_scan1(const int* __restrict__ cnt, int* rowptr,
                                               int* bsum, int N) {
    __shared__ int tmp[TPB];
    int t = threadIdx.x;
    int i = blockIdx.x * TPB + t;
    int v = (i < N) ? cnt[(size_t)i * CSTRIDE] : 0;
    tmp[t] = v;
    __syncthreads();
    for (int off = 1; off < TPB; off <<= 1) {
        int y = (t >= off) ? tmp[t - off] : 0;
        __syncthreads();
        tmp[t] += y;
        __syncthreads();
    }
    if (i < N) rowptr[i] = tmp[t] - v;
    if (t == TPB - 1) bsum[blockIdx.x] = tmp[t];
}

__global__ __launch_bounds__(TPB) void k_scan2(int* bsum, int nb) {
    __shared__ int tmp[TPB];
    int t = threadIdx.x;
    int v = (t < nb) ? bsum[t] : 0;
    tmp[t] = v;
    __syncthreads();
    for (int off = 1; off < TPB; off <<= 1) {
        int y = (t >= off) ? tmp[t - off] : 0;
        __syncthreads();
        tmp[t] += y;
        __syncthreads();
    }
    if (t < nb) bsum[t] = tmp[t] - v;
}

__global__ __launch_bounds__(TPB) void k_scan3(int* rowptr, const int* __restrict__ bsum,
                                               const int* __restrict__ cnt, float* dinv,
                                               int N, int total) {
    int i = blockIdx.x * TPB + threadIdx.x;
    if (i < N) {
        rowptr[i] += bsum[blockIdx.x];
        dinv[i] = 1.0f / sqrtf((float)(cnt[(size_t)i * CSTRIDE] + 1));  // +1 self-loop
    }
    if (i == 0) rowptr[N] = total;
}

// fused: blocks [0,nbF) fill CSR cols; blocks [nbF, nbF+nbS) rescale the
// layer-1 GEMM output by dinv (g' = dinv .* g), hidden under fill's scatter.
__global__ __launch_bounds__(TPB) void k_fill_scale(const int* __restrict__ src,
                                                    const int* __restrict__ dst,
                                                    const int* __restrict__ rowptr,
                                                    const u16* __restrict__ aux,
                                                    u16* __restrict__ cols, int E, int nbF,
                                                    u16* __restrict__ g,
                                                    const float* __restrict__ dinv, int N) {
    int b = blockIdx.x;
    if (b < nbF) {
        int e = (b * TPB + (int)threadIdx.x) * 4;
        if (e + 3 < E) {
            int4 s = *(const int4*)(src + e);
            int4 d = *(const int4*)(dst + e);
            ushort4 a = *(const ushort4*)(aux + e);
            cols[rowptr[d.x] + a.x] = (u16)s.x;
            cols[rowptr[d.y] + a.y] = (u16)s.y;
            cols[rowptr[d.z] + a.z] = (u16)s.z;
            cols[rowptr[d.w] + a.w] = (u16)s.w;
        } else {
            for (; e < E; ++e) cols[rowptr[dst[e]] + aux[e]] = (u16)src[e];
        }
    } else {
        int e8 = (b - nbF) * TPB + (int)threadIdx.x;  // 8-element unit
        if (e8 < N * 16) {
            int row = e8 >> 4;
            int off = (e8 & 15) * 8;
            float dv = dinv[row];
            u16* p = g + (size_t)row * 128 + off;
            uint4 v = *(uint4*)p;
            uint4 o;
            o.x = (u32)f2b(dv * b2f_lo(v.x)) | ((u32)f2b(dv * b2f_hi(v.x)) << 16);
            o.y = (u32)f2b(dv * b2f_lo(v.y)) | ((u32)f2b(dv * b2f_hi(v.y)) << 16);
            o.z = (u32)f2b(dv * b2f_lo(v.z)) | ((u32)f2b(dv * b2f_hi(v.z)) << 16);
            o.w = (u32)f2b(dv * b2f_lo(v.w)) | ((u32)f2b(dv * b2f_hi(v.w)) << 16);
            *(uint4*)p = o;
        }
    }
}

// W[128][128] f32 (k-major) -> Wt bf16 transposed + chunk-XOR-swizzled.
__device__ __forceinline__ void prepw_body(int bb, const float* __restrict__ Wa,
                                           const float* __restrict__ Wb,
                                           const float* __restrict__ Wc,
                                           u16* __restrict__ Wta, u16* __restrict__ Wtb,
                                           u16* __restrict__ Wtc) {
    int m = bb >> 3;
    const float* W = m == 0 ? Wa : (m == 1 ? Wb : Wc);
    u16* Wt = m == 0 ? Wta : (m == 1 ? Wtb : Wtc);
    int t = (bb & 7) * TPB + (int)threadIdx.x;
    int n = t >> 4, c = t & 15;
    u16x8 r;
#pragma unroll
    for (int j = 0; j < 8; ++j) r[j] = f2b(W[(8 * c + j) * 128 + n]);
    int cs = c ^ (n & 15);
    *(u16x8*)(Wt + n * 128 + cs * 8) = r;
}

// fused: zero padded counters; prep 3 W matrices; zero row N of bufA/bufB
// (the gather target for masked/padding edges).
__global__ __launch_bounds__(TPB) void k_zero_prep(int* cnt, int N, int nbZ4,
                                                   const float* __restrict__ Wa,
                                                   const float* __restrict__ Wb,
                                                   const float* __restrict__ Wc,
                                                   u16* __restrict__ Wta,
                                                   u16* __restrict__ Wtb,
                                                   u16* __restrict__ Wtc,
                                                   u16* __restrict__ bufA,
                                                   u16* __restrict__ bufB) {
    int b = blockIdx.x;
    if (b < nbZ4) {
        int i = b * TPB + (int)threadIdx.x;
        if (i < N * (CSTRIDE / 4)) ((int4*)cnt)[i] = (int4){0, 0, 0, 0};
    } else if (b < nbZ4 + 24) {
        prepw_body(b - nbZ4, Wa, Wb, Wc, Wta, Wtb, Wtc);
    } else {
        int t = threadIdx.x;
        uint4 z = (uint4){0, 0, 0, 0};
        if (t < 16) *(uint4*)(bufA + (size_t)N * 128 + t * 8) = z;
        else if (t < 32) *(uint4*)(bufB + (size_t)N * 128 + (t - 16) * 8) = z;
    }
}

// ---------------- MFMA GEMM: C[N][128] = (A[N][128] @ W) [* dinv row] ------
template <bool F32IN, bool SCALE>
__device__ __forceinline__ void gemm_body(int bid, const void* __restrict__ Ain,
                                          const u16* __restrict__ Wt,
                                          u16* __restrict__ C, int N,
                                          const float* __restrict__ dinv) {
    __shared__ u16 Ws[128 * 128];  // 32 KB, pre-swizzled chunks
    int t = threadIdx.x;
    {
        const uint4* s = (const uint4*)Wt;
        uint4* d = (uint4*)Ws;
#pragma unroll
        for (int i = 0; i < 8; ++i) d[t + 256 * i] = s[t + 256 * i];
    }
    __syncthreads();
    int wave = t >> 6, lane = t & 63;
    int li = lane & 15, lq = lane >> 4;
    int r0 = bid * 128 + wave * 32;
    f32x4 acc[2][8];
#pragma unroll
    for (int i = 0; i < 2; ++i)
#pragma unroll
        for (int f = 0; f < 8; ++f) acc[i][f] = (f32x4){0.f, 0.f, 0.f, 0.f};

    int ra = r0 + li, rb = ra + 16;
    size_t ra_c = (size_t)(ra < N ? ra : N - 1);
    size_t rb_c = (size_t)(rb < N ? rb : N - 1);
#pragma unroll
    for (int kc = 0; kc < 4; ++kc) {
        int koff = 32 * kc + 8 * lq;
        bf16x8 a0, a1;
        if constexpr (F32IN) {
            const float* A = (const float*)Ain;
            const float4* p0 = (const float4*)(A + ra_c * 128 + koff);
            const float4* p1 = (const float4*)(A + rb_c * 128 + koff);
            a0 = cvt8(p0[0], p0[1]);
            a1 = cvt8(p1[0], p1[1]);
        } else {
            const u16* A = (const u16*)Ain;
            a0 = *(const bf16x8*)(A + ra_c * 128 + koff);
            a1 = *(const bf16x8*)(A + rb_c * 128 + koff);
        }
#pragma unroll
        for (int f = 0; f < 8; ++f) {
            int n = 16 * f + li;
            int chunk = (4 * kc + lq) ^ li;  // n&15 == li
            bf16x8 b = *(const bf16x8*)(Ws + n * 128 + chunk * 8);
            acc[0][f] = __builtin_amdgcn_mfma_f32_16x16x32_bf16(a0, b, acc[0][f], 0, 0, 0);
            acc[1][f] = __builtin_amdgcn_mfma_f32_16x16x32_bf16(a1, b, acc[1][f], 0, 0, 0);
        }
    }
#pragma unroll
    for (int ri = 0; ri < 2; ++ri)
#pragma unroll
        for (int r = 0; r < 4; ++r) {
            int row = r0 + 16 * ri + 4 * lq + r;
            if (row < N) {
                float dv = 1.0f;
                if constexpr (SCALE) dv = dinv[row];
#pragma unroll
                for (int f = 0; f < 8; ++f)
                    C[(size_t)row * 128 + 16 * f + li] = f2b(dv * acc[ri][f][r]);
            }
        }
}

template <bool F32IN, bool SCALE>
__global__ __launch_bounds__(TPB) void k_gemm(const void* __restrict__ Ain,
                                              const u16* __restrict__ Wt,
                                              u16* __restrict__ C, int N,
                                              const float* __restrict__ dinv) {
    gemm_body<F32IN, SCALE>(blockIdx.x, Ain, Wt, C, N, dinv);
}

// fused: blocks [0,nbG) run layer-1 GEMM (f32 input, unscaled: dinv not yet
// known); blocks [nbG,..) run the CSR count+slot pass.
__global__ __launch_bounds__(TPB) void k_gemm1_count(const void* __restrict__ x,
                                                     const u16* __restrict__ Wt1,
                                                     u16* __restrict__ C, int N, int nbG,
                                                     const int* __restrict__ dst,
                                                     int* cnt, u16* __restrict__ aux, int E) {
    int b = blockIdx.x;
    if (b < nbG) {
        gemm_body<true, false>(b, x, Wt1, C, N, nullptr);
    } else {
        countslot_body(b - nbG, dst, cnt, aux, E);
    }
}

// ------- aggregate: h = relu(dn*(g'[node] + sum g'[col]) + b) -------------
// 16 lanes/node, 16 nodes/block. Per 64-edge supergroup: stage cols in regs,
// then a 2-deep pipeline of 8-wide gather chunks with counted vmcnt(8) waits
// (16 loads continuously in flight per wave). Static double buffers vA/vB.
// No coef math: GEMM output is dinv-prescaled; masked edges gather zero row N.
// Inside the pipelined region the only VMEM ops are our asm loads, so the
// counted waits are exact.
#define AGG_ISS(BUF, T)                                                    \
    {                                                                      \
        _Pragma("unroll") for (int u = 0; u < 8; ++u) {                    \
            int sl = 8 * (T) + u;                                          \
            int col = __shfl(cg[sl >> 4], sl & 15, 16);                    \
            const u16* p = g + (size_t)col * 128 + lane * 8;               \
            asm volatile("global_load_dwordx4 %0, %1, off sc0"             \
                         : "=v"(BUF[u]) : "v"(p));                         \
        }                                                                  \
    }
#define AGG_CONS(BUF)                                                      \
    {                                                                      \
        _Pragma("unroll") for (int u = 0; u < 8; ++u) {                    \
            a[0] += b2f_lo(BUF[u].x); a[1] += b2f_hi(BUF[u].x);            \
            a[2] += b2f_lo(BUF[u].y); a[3] += b2f_hi(BUF[u].y);            \
            a[4] += b2f_lo(BUF[u].z); a[5] += b2f_hi(BUF[u].z);            \
            a[6] += b2f_lo(BUF[u].w); a[7] += b2f_hi(BUF[u].w);            \
        }                                                                  \
    }
#define AGG_WAIT(n)                                                        \
    {                                                                      \
        asm volatile("s_waitcnt vmcnt(" #n ")" ::: "memory");              \
        __builtin_amdgcn_sched_barrier(0);                                 \
    }
#define AGG_STEP(T, CUR, NXT)                                              \
    if ((T) < nc) {                                                        \
        if ((T) + 1 < nc) { AGG_ISS(NXT, (T) + 1); AGG_WAIT(8); }          \
        else { AGG_WAIT(0); }                                              \
        AGG_CONS(CUR);                                                     \
    }

__global__ __launch_bounds__(TPB) void k_agg(const u16* __restrict__ g,
                                             const u16* __restrict__ cols,
                                             const int* __restrict__ rowptr,
                                             const float* __restrict__ dinv,
                                             const float* __restrict__ bias,
                                             u16* __restrict__ hout, int N) {
    int node = blockIdx.x * 16 + (threadIdx.x >> 4);
    int lane = threadIdx.x & 15;
    if (node >= N) return;
    int beg = rowptr[node], end = rowptr[node + 1];
    float dn = dinv[node];
    float a[8];
    {   // self term: g'[node] (dn applied once at the end)
        uint4 vs = *(const uint4*)(g + (size_t)node * 128 + lane * 8);
        a[0] = b2f_lo(vs.x); a[1] = b2f_hi(vs.x);
        a[2] = b2f_lo(vs.y); a[3] = b2f_hi(vs.y);
        a[4] = b2f_lo(vs.z); a[5] = b2f_hi(vs.z);
        a[6] = b2f_lo(vs.w); a[7] = b2f_hi(vs.w);
    }
    for (int sb = beg; sb < end; sb += 64) {
        int m = end - sb;
        if (m > 64) m = 64;
        // ---- stage up to 64 cols (4 per lane); masked -> zero row N ----
        int cg[4];
#pragma unroll
        for (int q = 0; q < 4; ++q) {
            int off = 16 * q + lane;
            int c = (int)cols[sb + (off < m ? off : 0)];
            cg[q] = (off < m) ? c : N;
        }
        int nc = (m + 7) >> 3;  // 1..8 chunks of 8 edges
        uint4 vA[8], vB[8];
        AGG_ISS(vA, 0);
        AGG_STEP(0, vA, vB)
        AGG_STEP(1, vB, vA)
        AGG_STEP(2, vA, vB)
        AGG_STEP(3, vB, vA)
        AGG_STEP(4, vA, vB)
        AGG_STEP(5, vB, vA)
        AGG_STEP(6, vA, vB)
        AGG_STEP(7, vB, vA)
    }
    const float4* bp = (const float4*)(bias + lane * 8);
    float4 b0 = bp[0], b1 = bp[1];
    a[0] = fmaxf(fmaf(dn, a[0], b0.x), 0.f); a[1] = fmaxf(fmaf(dn, a[1], b0.y), 0.f);
    a[2] = fmaxf(fmaf(dn, a[2], b0.z), 0.f); a[3] = fmaxf(fmaf(dn, a[3], b0.w), 0.f);
    a[4] = fmaxf(fmaf(dn, a[4], b1.x), 0.f); a[5] = fmaxf(fmaf(dn, a[5], b1.y), 0.f);
    a[6] = fmaxf(fmaf(dn, a[6], b1.z), 0.f); a[7] = fmaxf(fmaf(dn, a[7], b1.w), 0.f);
    uint4 o;
    o.x = (u32)f2b(a[0]) | ((u32)f2b(a[1]) << 16);
    o.y = (u32)f2b(a[2]) | ((u32)f2b(a[3]) << 16);
    o.z = (u32)f2b(a[4]) | ((u32)f2b(a[5]) << 16);
    o.w = (u32)f2b(a[6]) | ((u32)f2b(a[7]) << 16);
    *(uint4*)(hout + (size_t)node * 128 + lane * 8) = o;
}

// ---------------- pool (bounds fused: per-block binary search) ----------------
__global__ __launch_bounds__(128) void k_pool(const u16* __restrict__ h,
                                              const int* __restrict__ batch,
                                              float* __restrict__ out, int N, int G) {
    int g = blockIdx.x;
    int f = threadIdx.x;
    int beg, end;
    {
        int lo = 0, hi = N;
        while (lo < hi) { int m = (lo + hi) >> 1; if (batch[m] < g) lo = m + 1; else hi = m; }
        beg = lo;
        lo = 0; hi = N;
        int g1 = g + 1;
        while (lo < hi) { int m = (lo + hi) >> 1; if (batch[m] < g1) lo = m + 1; else hi = m; }
        end = lo;
    }
    float acc = 0.0f;
    for (int n = beg; n < end; ++n)
        acc += b2f_lo((u32)h[(size_t)n * 128 + f]);
    int c = end - beg; if (c < 1) c = 1;
    out[(size_t)g * 128 + f] = acc / (float)c;
}

extern "C" void kernel_launch(void* const* d_in, const int* in_sizes, int n_in,
                              void* d_out, int out_size, void* d_ws, size_t ws_size,
                              hipStream_t stream) {
    const float* x  = (const float*)d_in[0];
    const float* W1 = (const float*)d_in[2];
    const float* b1 = (const float*)d_in[3];
    const float* W2 = (const float*)d_in[4];
    const float* b2 = (const float*)d_in[5];
    const float* W3 = (const float*)d_in[6];
    const float* b3 = (const float*)d_in[7];
    const int* ei    = (const int*)d_in[8];
    const int* batch = (const int*)d_in[9];

    int N = in_sizes[0] / 128;
    int E = in_sizes[8] / 2;
    int G = out_size / 128;
    const int* src = ei;
    const int* dst = ei + E;

    char* w = (char*)d_ws;
    auto alloc = [&](size_t bytes) -> void* {
        void* p = (void*)w;
        w += (bytes + 255) & ~(size_t)255;
        return p;
    };
    int*   cnt    = (int*)alloc((size_t)N * CSTRIDE * 4);
    u16*   aux    = (u16*)alloc((size_t)E * 2);
    int*   rowptr = (int*)alloc((size_t)(N + 1) * 4);
    float* dinv   = (float*)alloc((size_t)N * 4);
    int*   bsum   = (int*)alloc(4096);
    u16*   cols   = (u16*)alloc((size_t)E * 2);
    u16*   Wt1    = (u16*)alloc(128 * 128 * 2);
    u16*   Wt2    = (u16*)alloc(128 * 128 * 2);
    u16*   Wt3    = (u16*)alloc(128 * 128 * 2);
    u16*   bufA   = (u16*)alloc((size_t)(N + 1) * 128 * 2);  // +1 zero row
    u16*   bufB   = (u16*)alloc((size_t)(N + 1) * 128 * 2);

    int nbN = (N + TPB - 1) / TPB;
    int nbE4 = (E / 4 + TPB - 1) / TPB;
    int nbG = (N + 127) / 128;
    int nbZ4 = (N * (CSTRIDE / 4) + TPB - 1) / TPB;
    int nbS = (N * 16 + TPB - 1) / TPB;
    int nbA = (N + 15) / 16;

    // ---- zero padded counters + weight prep + zero-row init (fused) ----
    k_zero_prep<<<nbZ4 + 24 + 1, TPB, 0, stream>>>(cnt, N, nbZ4, W1, W2, W3,
                                                   Wt1, Wt2, Wt3, bufA, bufB);
    // ---- layer-1 GEMM overlapped with CSR count+slot ----
    k_gemm1_count<<<nbG + nbE4, TPB, 0, stream>>>(x, Wt1, bufA, N, nbG, dst, cnt, aux, E);
    // ---- rowptr scan; fill fused with layer-1 dinv rescale ----
    k_scan1<<<nbN, TPB, 0, stream>>>(cnt, rowptr, bsum, N);
    k_scan2<<<1, TPB, 0, stream>>>(bsum, nbN);
    k_scan3<<<nbN, TPB, 0, stream>>>(rowptr, bsum, cnt, dinv, N, E);
    k_fill_scale<<<nbE4 + nbS, TPB, 0, stream>>>(src, dst, rowptr, aux, cols, E, nbE4,
                                                 bufA, dinv, N);

    // ---- 3 GCN layers ----
    k_agg<<<nbA, TPB, 0, stream>>>(bufA, cols, rowptr, dinv, b1, bufB, N);
    k_gemm<false, true><<<nbG, TPB, 0, stream>>>(bufB, Wt2, bufA, N, dinv);
    k_agg<<<nbA, TPB, 0, stream>>>(bufA, cols, rowptr, dinv, b2, bufB, N);
    k_gemm<false, true><<<nbG, TPB, 0, stream>>>(bufB, Wt3, bufA, N, dinv);
    k_agg<<<nbA, TPB, 0, stream>>>(bufA, cols, rowptr, dinv, b3, bufB, N);

    // ---- mean pool ----
    k_pool<<<G, 128, 0, stream>>>(bufB, batch, (float*)d_out, N, G);
}

// Round 6
// 196.797 us; speedup vs baseline: 1.4800x; 1.0809x over previous
//
#include <hip/hip_runtime.h>
#include <hip/hip_bf16.h>

// GCN backbone, bf16 datapath:
//   layer: g' = dinv .* (h@W) (MFMA bf16, f32 acc, dinv-prescaled bf16 out)
//          h  = relu(dn*(g'[node] + sum_col g'[col]) + b)
// Prescale folds the symmetric norm into the GEMM epilogue: agg has NO
// per-edge dinv gathers and NO coef multiplies (masked edges gather the
// zero row N). Agg runs as TWO serial half-feature passes (64 features =
// 128B each): per-pass gather working set 6.4MB -> per-XCD L2 hit ~65%
// (vs 33% full-width), cutting average gather service latency. Within a
// pass: 8 lanes/node, 2-deep pipeline of 8-wide gather chunks with counted
// vmcnt(8) waits (16 loads in flight/wave), static double buffers.
// CSR: u16 cols, padded counters (1/64B line) for the atomic count pass,
// count fused with layer-1 GEMM, zero with prepW, dinv-rescale with fill,
// scan2 folded into scan3. Pool: 4 row-streams/block + LDS reduce.

#define TPB 256
#define CSTRIDE 16  // cnt padding: one counter per 64B line
typedef unsigned short u16;
typedef unsigned int u32;
typedef __attribute__((ext_vector_type(8))) __bf16 bf16x8;
typedef __attribute__((ext_vector_type(8))) u16 u16x8;
typedef __attribute__((ext_vector_type(4))) float f32x4;

__device__ __forceinline__ u16 f2b(float f) {
    __bf16 b = (__bf16)f;                 // RNE on gfx950
    return __builtin_bit_cast(u16, b);
}
__device__ __forceinline__ float b2f_lo(u32 w) { return __builtin_bit_cast(float, w << 16); }
__device__ __forceinline__ float b2f_hi(u32 w) { return __builtin_bit_cast(float, w & 0xffff0000u); }

__device__ __forceinline__ bf16x8 cvt8(float4 u0, float4 u1) {
    u16x8 r;
    r[0] = f2b(u0.x); r[1] = f2b(u0.y); r[2] = f2b(u0.z); r[3] = f2b(u0.w);
    r[4] = f2b(u1.x); r[5] = f2b(u1.y); r[6] = f2b(u1.z); r[7] = f2b(u1.w);
    return __builtin_bit_cast(bf16x8, r);
}

// ---------------- CSR build pieces ----------------
__device__ __forceinline__ void countslot_body(int bid, const int* __restrict__ dst,
                                               int* cnt, u16* __restrict__ aux, int E) {
    int e = (bid * TPB + (int)threadIdx.x) * 4;
    if (e + 3 < E) {
        int4 d = *(const int4*)(dst + e);
        ushort4 a;
        a.x = (u16)atomicAdd(&cnt[d.x * CSTRIDE], 1);
        a.y = (u16)atomicAdd(&cnt[d.y * CSTRIDE], 1);
        a.z = (u16)atomicAdd(&cnt[d.z * CSTRIDE], 1);
        a.w = (u16)atomicAdd(&cnt[d.w * CSTRIDE], 1);
        *(ushort4*)(aux + e) = a;
    } else {
        for (; e < E; ++e) aux[e] = (u16)atomicAdd(&cnt[dst[e] * CSTRIDE], 1);
    }
}

__global__ __launch_bounds__(TPB) void k_scan1(const int* __restrict__ cnt, int* rowptr,
                                               int* bsum, int N) {
    __shared__ int tmp[TPB];
    int t = threadIdx.x;
    int i = blockIdx.x * TPB + t;
    int v = (i < N) ? cnt[(size_t)i * CSTRIDE] : 0;
    tmp[t] = v;
    __syncthreads();
    for (int off = 1; off < TPB; off <<= 1) {
        int y = (t >= off) ? tmp[t - off] : 0;
        __syncthreads();
        tmp[t] += y;
        __syncthreads();
    }
    if (i < N) rowptr[i] = tmp[t] - v;
    if (t == TPB - 1) bsum[blockIdx.x] = tmp[t];
}

// scan2 folded in: each block computes the exclusive prefix of bsum[0..b)
// itself (nb <= 256 guaranteed: N=50000 -> 196 blocks).
__global__ __launch_bounds__(TPB) void k_scan3(int* rowptr, const int* __restrict__ bsum,
                                               const int* __restrict__ cnt, float* dinv,
                                               int N, int total, int nb) {
    __shared__ int tmp[TPB];
    int t = threadIdx.x;
    tmp[t] = (t < nb) ? bsum[t] : 0;
    __syncthreads();
    for (int off = 1; off < TPB; off <<= 1) {
        int y = (t >= off) ? tmp[t - off] : 0;
        __syncthreads();
        tmp[t] += y;
        __syncthreads();
    }
    int pre = (blockIdx.x == 0) ? 0 : tmp[blockIdx.x - 1];
    int i = blockIdx.x * TPB + t;
    if (i < N) {
        rowptr[i] += pre;
        dinv[i] = 1.0f / sqrtf((float)(cnt[(size_t)i * CSTRIDE] + 1));  // +1 self-loop
    }
    if (i == 0) rowptr[N] = total;
}

// fused: blocks [0,nbF) fill CSR cols; blocks [nbF, nbF+nbS) rescale the
// layer-1 GEMM output by dinv (g' = dinv .* g), hidden under fill's scatter.
__global__ __launch_bounds__(TPB) void k_fill_scale(const int* __restrict__ src,
                                                    const int* __restrict__ dst,
                                                    const int* __restrict__ rowptr,
                                                    const u16* __restrict__ aux,
                                                    u16* __restrict__ cols, int E, int nbF,
                                                    u16* __restrict__ g,
                                                    const float* __restrict__ dinv, int N) {
    int b = blockIdx.x;
    if (b < nbF) {
        int e = (b * TPB + (int)threadIdx.x) * 4;
        if (e + 3 < E) {
            int4 s = *(const int4*)(src + e);
            int4 d = *(const int4*)(dst + e);
            ushort4 a = *(const ushort4*)(aux + e);
            cols[rowptr[d.x] + a.x] = (u16)s.x;
            cols[rowptr[d.y] + a.y] = (u16)s.y;
            cols[rowptr[d.z] + a.z] = (u16)s.z;
            cols[rowptr[d.w] + a.w] = (u16)s.w;
        } else {
            for (; e < E; ++e) cols[rowptr[dst[e]] + aux[e]] = (u16)src[e];
        }
    } else {
        int e8 = (b - nbF) * TPB + (int)threadIdx.x;  // 8-element unit
        if (e8 < N * 16) {
            int row = e8 >> 4;
            int off = (e8 & 15) * 8;
            float dv = dinv[row];
            u16* p = g + (size_t)row * 128 + off;
            uint4 v = *(uint4*)p;
            uint4 o;
            o.x = (u32)f2b(dv * b2f_lo(v.x)) | ((u32)f2b(dv * b2f_hi(v.x)) << 16);
            o.y = (u32)f2b(dv * b2f_lo(v.y)) | ((u32)f2b(dv * b2f_hi(v.y)) << 16);
            o.z = (u32)f2b(dv * b2f_lo(v.z)) | ((u32)f2b(dv * b2f_hi(v.z)) << 16);
            o.w = (u32)f2b(dv * b2f_lo(v.w)) | ((u32)f2b(dv * b2f_hi(v.w)) << 16);
            *(uint4*)p = o;
        }
    }
}

// W[128][128] f32 (k-major) -> Wt bf16 transposed + chunk-XOR-swizzled.
__device__ __forceinline__ void prepw_body(int bb, const float* __restrict__ Wa,
                                           const float* __restrict__ Wb,
                                           const float* __restrict__ Wc,
                                           u16* __restrict__ Wta, u16* __restrict__ Wtb,
                                           u16* __restrict__ Wtc) {
    int m = bb >> 3;
    const float* W = m == 0 ? Wa : (m == 1 ? Wb : Wc);
    u16* Wt = m == 0 ? Wta : (m == 1 ? Wtb : Wtc);
    int t = (bb & 7) * TPB + (int)threadIdx.x;
    int n = t >> 4, c = t & 15;
    u16x8 r;
#pragma unroll
    for (int j = 0; j < 8; ++j) r[j] = f2b(W[(8 * c + j) * 128 + n]);
    int cs = c ^ (n & 15);
    *(u16x8*)(Wt + n * 128 + cs * 8) = r;
}

// fused: zero padded counters; prep 3 W matrices; zero row N of bufA/bufB
// (the gather target for masked/padding edges).
__global__ __launch_bounds__(TPB) void k_zero_prep(int* cnt, int N, int nbZ4,
                                                   const float* __restrict__ Wa,
                                                   const float* __restrict__ Wb,
                                                   const float* __restrict__ Wc,
                                                   u16* __restrict__ Wta,
                                                   u16* __restrict__ Wtb,
                                                   u16* __restrict__ Wtc,
                                                   u16* __restrict__ bufA,
                                                   u16* __restrict__ bufB) {
    int b = blockIdx.x;
    if (b < nbZ4) {
        int i = b * TPB + (int)threadIdx.x;
        if (i < N * (CSTRIDE / 4)) ((int4*)cnt)[i] = (int4){0, 0, 0, 0};
    } else if (b < nbZ4 + 24) {
        prepw_body(b - nbZ4, Wa, Wb, Wc, Wta, Wtb, Wtc);
    } else {
        int t = threadIdx.x;
        uint4 z = (uint4){0, 0, 0, 0};
        if (t < 16) *(uint4*)(bufA + (size_t)N * 128 + t * 8) = z;
        else if (t < 32) *(uint4*)(bufB + (size_t)N * 128 + (t - 16) * 8) = z;
    }
}

// ---------------- MFMA GEMM: C[N][128] = (A[N][128] @ W) [* dinv row] ------
template <bool F32IN, bool SCALE>
__device__ __forceinline__ void gemm_body(int bid, const void* __restrict__ Ain,
                                          const u16* __restrict__ Wt,
                                          u16* __restrict__ C, int N,
                                          const float* __restrict__ dinv) {
    __shared__ u16 Ws[128 * 128];  // 32 KB, pre-swizzled chunks
    int t = threadIdx.x;
    {
        const uint4* s = (const uint4*)Wt;
        uint4* d = (uint4*)Ws;
#pragma unroll
        for (int i = 0; i < 8; ++i) d[t + 256 * i] = s[t + 256 * i];
    }
    __syncthreads();
    int wave = t >> 6, lane = t & 63;
    int li = lane & 15, lq = lane >> 4;
    int r0 = bid * 128 + wave * 32;
    f32x4 acc[2][8];
#pragma unroll
    for (int i = 0; i < 2; ++i)
#pragma unroll
        for (int f = 0; f < 8; ++f) acc[i][f] = (f32x4){0.f, 0.f, 0.f, 0.f};

    int ra = r0 + li, rb = ra + 16;
    size_t ra_c = (size_t)(ra < N ? ra : N - 1);
    size_t rb_c = (size_t)(rb < N ? rb : N - 1);
#pragma unroll
    for (int kc = 0; kc < 4; ++kc) {
        int koff = 32 * kc + 8 * lq;
        bf16x8 a0, a1;
        if constexpr (F32IN) {
            const float* A = (const float*)Ain;
            const float4* p0 = (const float4*)(A + ra_c * 128 + koff);
            const float4* p1 = (const float4*)(A + rb_c * 128 + koff);
            a0 = cvt8(p0[0], p0[1]);
            a1 = cvt8(p1[0], p1[1]);
        } else {
            const u16* A = (const u16*)Ain;
            a0 = *(const bf16x8*)(A + ra_c * 128 + koff);
            a1 = *(const bf16x8*)(A + rb_c * 128 + koff);
        }
#pragma unroll
        for (int f = 0; f < 8; ++f) {
            int n = 16 * f + li;
            int chunk = (4 * kc + lq) ^ li;  // n&15 == li
            bf16x8 b = *(const bf16x8*)(Ws + n * 128 + chunk * 8);
            acc[0][f] = __builtin_amdgcn_mfma_f32_16x16x32_bf16(a0, b, acc[0][f], 0, 0, 0);
            acc[1][f] = __builtin_amdgcn_mfma_f32_16x16x32_bf16(a1, b, acc[1][f], 0, 0, 0);
        }
    }
#pragma unroll
    for (int ri = 0; ri < 2; ++ri)
#pragma unroll
        for (int r = 0; r < 4; ++r) {
            int row = r0 + 16 * ri + 4 * lq + r;
            if (row < N) {
                float dv = 1.0f;
                if constexpr (SCALE) dv = dinv[row];
#pragma unroll
                for (int f = 0; f < 8; ++f)
                    C[(size_t)row * 128 + 16 * f + li] = f2b(dv * acc[ri][f][r]);
            }
        }
}

template <bool F32IN, bool SCALE>
__global__ __launch_bounds__(TPB) void k_gemm(const void* __restrict__ Ain,
                                              const u16* __restrict__ Wt,
                                              u16* __restrict__ C, int N,
                                              const float* __restrict__ dinv) {
    gemm_body<F32IN, SCALE>(blockIdx.x, Ain, Wt, C, N, dinv);
}

// fused: blocks [0,nbG) run layer-1 GEMM (f32 input, unscaled: dinv not yet
// known); blocks [nbG,..) run the CSR count+slot pass.
__global__ __launch_bounds__(TPB) void k_gemm1_count(const void* __restrict__ x,
                                                     const u16* __restrict__ Wt1,
                                                     u16* __restrict__ C, int N, int nbG,
                                                     const int* __restrict__ dst,
                                                     int* cnt, u16* __restrict__ aux, int E) {
    int b = blockIdx.x;
    if (b < nbG) {
        gemm_body<true, false>(b, x, Wt1, C, N, nullptr);
    } else {
        countslot_body(b - nbG, dst, cnt, aux, E);
    }
}

// ------- aggregate (half-feature pass): h = relu(dn*(self+sum)+b) ---------
// hoff in {0,64}: 64 features = 128B per row. 8 lanes/node, 32 nodes/block.
// Per 64-edge supergroup: stage cols in regs, 2-deep pipeline of 8-wide
// gather chunks with counted vmcnt(8) waits (16 loads in flight per wave).
// Static double buffers; no coef math (GEMM output dinv-prescaled); masked
// edges gather zero row N. Inside the pipelined region the only VMEM ops
// are our asm loads, so counted waits are exact.
#define AGG_ISS(BUF, T)                                                    \
    {                                                                      \
        _Pragma("unroll") for (int u = 0; u < 8; ++u) {                    \
            int col = __shfl(cg[T], u, 8);                                 \
            const u16* p = g + (size_t)col * 128 + fo;                     \
            asm volatile("global_load_dwordx4 %0, %1, off sc0"             \
                         : "=v"(BUF[u]) : "v"(p));                         \
        }                                                                  \
    }
#define AGG_CONS(BUF)                                                      \
    {                                                                      \
        _Pragma("unroll") for (int u = 0; u < 8; ++u) {                    \
            a[0] += b2f_lo(BUF[u].x); a[1] += b2f_hi(BUF[u].x);            \
            a[2] += b2f_lo(BUF[u].y); a[3] += b2f_hi(BUF[u].y);            \
            a[4] += b2f_lo(BUF[u].z); a[5] += b2f_hi(BUF[u].z);            \
            a[6] += b2f_lo(BUF[u].w); a[7] += b2f_hi(BUF[u].w);            \
        }                                                                  \
    }
#define AGG_WAIT(n)                                                        \
    {                                                                      \
        asm volatile("s_waitcnt vmcnt(" #n ")" ::: "memory");              \
        __builtin_amdgcn_sched_barrier(0);                                 \
    }
#define AGG_STEP(T, CUR, NXT)                                              \
    if ((T) < nc) {                                                        \
        if ((T) + 1 < nc) { AGG_ISS(NXT, (T) + 1); AGG_WAIT(8); }          \
        else { AGG_WAIT(0); }                                              \
        AGG_CONS(CUR);                                                     \
    }

__global__ __launch_bounds__(TPB) void k_agg(const u16* __restrict__ g,
                                             const u16* __restrict__ cols,
                                             const int* __restrict__ rowptr,
                                             const float* __restrict__ dinv,
                                             const float* __restrict__ bias,
                                             u16* __restrict__ hout, int N, int hoff) {
    int node = blockIdx.x * 32 + ((int)threadIdx.x >> 3);
    int lane = threadIdx.x & 7;
    if (node >= N) return;
    int fo = hoff + lane * 8;  // u16 offset within row
    int beg = rowptr[node], end = rowptr[node + 1];
    float dn = dinv[node];
    float a[8];
    {   // self term: g'[node] (dn applied once at the end)
        uint4 vs = *(const uint4*)(g + (size_t)node * 128 + fo);
        a[0] = b2f_lo(vs.x); a[1] = b2f_hi(vs.x);
        a[2] = b2f_lo(vs.y); a[3] = b2f_hi(vs.y);
        a[4] = b2f_lo(vs.z); a[5] = b2f_hi(vs.z);
        a[6] = b2f_lo(vs.w); a[7] = b2f_hi(vs.w);
    }
    for (int sb = beg; sb < end; sb += 64) {
        int m = end - sb;
        if (m > 64) m = 64;
        // ---- stage up to 64 cols (8 per lane); masked -> zero row N ----
        int cg[8];
#pragma unroll
        for (int q = 0; q < 8; ++q) {
            int off = 8 * q + lane;
            int c = (int)cols[sb + (off < m ? off : 0)];
            cg[q] = (off < m) ? c : N;
        }
        int nc = (m + 7) >> 3;  // 1..8 chunks of 8 edges
        uint4 vA[8], vB[8];
        AGG_ISS(vA, 0);
        AGG_STEP(0, vA, vB)
        AGG_STEP(1, vB, vA)
        AGG_STEP(2, vA, vB)
        AGG_STEP(3, vB, vA)
        AGG_STEP(4, vA, vB)
        AGG_STEP(5, vB, vA)
        AGG_STEP(6, vA, vB)
        AGG_STEP(7, vB, vA)
    }
    const float4* bp = (const float4*)(bias + fo);
    float4 b0 = bp[0], b1 = bp[1];
    a[0] = fmaxf(fmaf(dn, a[0], b0.x), 0.f); a[1] = fmaxf(fmaf(dn, a[1], b0.y), 0.f);
    a[2] = fmaxf(fmaf(dn, a[2], b0.z), 0.f); a[3] = fmaxf(fmaf(dn, a[3], b0.w), 0.f);
    a[4] = fmaxf(fmaf(dn, a[4], b1.x), 0.f); a[5] = fmaxf(fmaf(dn, a[5], b1.y), 0.f);
    a[6] = fmaxf(fmaf(dn, a[6], b1.z), 0.f); a[7] = fmaxf(fmaf(dn, a[7], b1.w), 0.f);
    uint4 o;
    o.x = (u32)f2b(a[0]) | ((u32)f2b(a[1]) << 16);
    o.y = (u32)f2b(a[2]) | ((u32)f2b(a[3]) << 16);
    o.z = (u32)f2b(a[4]) | ((u32)f2b(a[5]) << 16);
    o.w = (u32)f2b(a[6]) | ((u32)f2b(a[7]) << 16);
    *(uint4*)(hout + (size_t)node * 128 + fo) = o;
}

// ---------------- pool: 4 row-streams/block, u32 loads, LDS reduce --------
__global__ __launch_bounds__(TPB) void k_pool(const u16* __restrict__ h,
                                              const int* __restrict__ batch,
                                              float* __restrict__ out, int N, int G) {
    int g = blockIdx.x;
    int w = threadIdx.x & 63;    // u32 word (2 features)
    int rid = threadIdx.x >> 6;  // 4 row streams
    int beg, end;
    {
        int lo = 0, hi = N;
        while (lo < hi) { int m = (lo + hi) >> 1; if (batch[m] < g) lo = m + 1; else hi = m; }
        beg = lo;
        lo = 0; hi = N;
        int g1 = g + 1;
        while (lo < hi) { int m = (lo + hi) >> 1; if (batch[m] < g1) lo = m + 1; else hi = m; }
        end = lo;
    }
    const u32* h32 = (const u32*)h;
    float a0 = 0.f, a1 = 0.f;
#pragma unroll 2
    for (int n = beg + rid; n < end; n += 4) {
        u32 v = h32[(size_t)n * 64 + w];
        a0 += b2f_lo(v); a1 += b2f_hi(v);
    }
    __shared__ float red[4][64][2];
    red[rid][w][0] = a0;
    red[rid][w][1] = a1;
    __syncthreads();
    if (rid == 0) {
        a0 = red[0][w][0] + red[1][w][0] + red[2][w][0] + red[3][w][0];
        a1 = red[0][w][1] + red[1][w][1] + red[2][w][1] + red[3][w][1];
        int c = end - beg; if (c < 1) c = 1;
        float inv = 1.0f / (float)c;
        out[(size_t)g * 128 + 2 * w]     = a0 * inv;
        out[(size_t)g * 128 + 2 * w + 1] = a1 * inv;
    }
}

extern "C" void kernel_launch(void* const* d_in, const int* in_sizes, int n_in,
                              void* d_out, int out_size, void* d_ws, size_t ws_size,
                              hipStream_t stream) {
    const float* x  = (const float*)d_in[0];
    const float* W1 = (const float*)d_in[2];
    const float* b1 = (const float*)d_in[3];
    const float* W2 = (const float*)d_in[4];
    const float* b2 = (const float*)d_in[5];
    const float* W3 = (const float*)d_in[6];
    const float* b3 = (const float*)d_in[7];
    const int* ei    = (const int*)d_in[8];
    const int* batch = (const int*)d_in[9];

    int N = in_sizes[0] / 128;
    int E = in_sizes[8] / 2;
    int G = out_size / 128;
    const int* src = ei;
    const int* dst = ei + E;

    char* w = (char*)d_ws;
    auto alloc = [&](size_t bytes) -> void* {
        void* p = (void*)w;
        w += (bytes + 255) & ~(size_t)255;
        return p;
    };
    int*   cnt    = (int*)alloc((size_t)N * CSTRIDE * 4);
    u16*   aux    = (u16*)alloc((size_t)E * 2);
    int*   rowptr = (int*)alloc((size_t)(N + 1) * 4);
    float* dinv   = (float*)alloc((size_t)N * 4);
    int*   bsum   = (int*)alloc(4096);
    u16*   cols   = (u16*)alloc((size_t)E * 2);
    u16*   Wt1    = (u16*)alloc(128 * 128 * 2);
    u16*   Wt2    = (u16*)alloc(128 * 128 * 2);
    u16*   Wt3    = (u16*)alloc(128 * 128 * 2);
    u16*   bufA   = (u16*)alloc((size_t)(N + 1) * 128 * 2);  // +1 zero row
    u16*   bufB   = (u16*)alloc((size_t)(N + 1) * 128 * 2);

    int nbN = (N + TPB - 1) / TPB;
    int nbE4 = (E / 4 + TPB - 1) / TPB;
    int nbG = (N + 127) / 128;
    int nbZ4 = (N * (CSTRIDE / 4) + TPB - 1) / TPB;
    int nbS = (N * 16 + TPB - 1) / TPB;
    int nbA = (N + 31) / 32;

    // ---- zero padded counters + weight prep + zero-row init (fused) ----
    k_zero_prep<<<nbZ4 + 24 + 1, TPB, 0, stream>>>(cnt, N, nbZ4, W1, W2, W3,
                                                   Wt1, Wt2, Wt3, bufA, bufB);
    // ---- layer-1 GEMM overlapped with CSR count+slot ----
    k_gemm1_count<<<nbG + nbE4, TPB, 0, stream>>>(x, Wt1, bufA, N, nbG, dst, cnt, aux, E);
    // ---- rowptr scan (scan2 folded into scan3); fill + layer-1 rescale ----
    k_scan1<<<nbN, TPB, 0, stream>>>(cnt, rowptr, bsum, N);
    k_scan3<<<nbN, TPB, 0, stream>>>(rowptr, bsum, cnt, dinv, N, E, nbN);
    k_fill_scale<<<nbE4 + nbS, TPB, 0, stream>>>(src, dst, rowptr, aux, cols, E, nbE4,
                                                 bufA, dinv, N);

    // ---- 3 GCN layers (agg = two serial half-feature passes) ----
    k_agg<<<nbA, TPB, 0, stream>>>(bufA, cols, rowptr, dinv, b1, bufB, N, 0);
    k_agg<<<nbA, TPB, 0, stream>>>(bufA, cols, rowptr, dinv, b1, bufB, N, 64);
    k_gemm<false, true><<<nbG, TPB, 0, stream>>>(bufB, Wt2, bufA, N, dinv);
    k_agg<<<nbA, TPB, 0, stream>>>(bufA, cols, rowptr, dinv, b2, bufB, N, 0);
    k_agg<<<nbA, TPB, 0, stream>>>(bufA, cols, rowptr, dinv, b2, bufB, N, 64);
    k_gemm<false, true><<<nbG, TPB, 0, stream>>>(bufB, Wt3, bufA, N, dinv);
    k_agg<<<nbA, TPB, 0, stream>>>(bufA, cols, rowptr, dinv, b3, bufB, N, 0);
    k_agg<<<nbA, TPB, 0, stream>>>(bufA, cols, rowptr, dinv, b3, bufB, N, 64);

    // ---- mean pool ----
    k_pool<<<G, TPB, 0, stream>>>(bufB, batch, (float*)d_out, N, G);
}